// Round 5
// baseline (271.889 us; speedup 1.0000x reference)
//
#include <hip/hip_runtime.h>
#include <hip/hip_bf16.h>
#include <math.h>

#define IN_DIM 128
#define OUT_DIM 64
#define NEG_SLOPE 0.2f

#define ROWS_PER_WAVE 8
#define ROWS_PER_BLOCK 32     // 4 waves/block

#define SCAN_ITEMS 4
#define SCAN_BLOCK 1024
#define SCAN_CHUNK (SCAN_BLOCK * SCAN_ITEMS)   // 4096

// ---------------------------------------------------------------- GEMM
// h(bf16) = X@W, el = h@a_l, er = h@a_r (fp32 accumulators).
// 8 rows per wave. X read directly from global at wave-uniform addresses
// (one broadcast fetch per float4, no LDS round-trip). W in LDS (32 KB),
// read as 4 conflict-free ds_read_b32 per k-quad, shared across 8 rows.
__global__ __launch_bounds__(256) void gemm_kernel(
        const float* __restrict__ X, const float* __restrict__ W,
        const float* __restrict__ a_l, const float* __restrict__ a_r,
        __hip_bfloat16* __restrict__ h, float* __restrict__ el, float* __restrict__ er,
        int n)
{
    __shared__ float Wl[IN_DIM * OUT_DIM];   // 32 KB
    const int tid  = threadIdx.x;
    const int lane = tid & 63;
    // force wave index into an SGPR so X addresses are provably wave-uniform
    const int wv = __builtin_amdgcn_readfirstlane(tid >> 6);

    // stage W cooperatively (2048 float4, coalesced)
    {
        const float4* W4  = (const float4*)W;
        float4*       Wl4 = (float4*)Wl;
        #pragma unroll
        for (int i = 0; i < 8; ++i)
            Wl4[i * 256 + tid] = W4[i * 256 + tid];
    }
    __syncthreads();

    const int row0 = blockIdx.x * ROWS_PER_BLOCK + wv * ROWS_PER_WAVE;
    if (row0 >= n) return;
    const float* __restrict__ Xr = X + (size_t)row0 * IN_DIM;

    float acc[ROWS_PER_WAVE] = {};
    if (row0 + ROWS_PER_WAVE <= n) {
        #pragma unroll 2
        for (int kq = 0; kq < IN_DIM / 4; ++kq) {
            const int k = kq * 4;
            const float w0 = Wl[(k    ) * OUT_DIM + lane];
            const float w1 = Wl[(k + 1) * OUT_DIM + lane];
            const float w2 = Wl[(k + 2) * OUT_DIM + lane];
            const float w3 = Wl[(k + 3) * OUT_DIM + lane];
            #pragma unroll
            for (int r = 0; r < ROWS_PER_WAVE; ++r) {
                const float4 x = *(const float4*)(Xr + r * IN_DIM + k);  // uniform broadcast
                acc[r] = fmaf(x.x, w0, acc[r]);
                acc[r] = fmaf(x.y, w1, acc[r]);
                acc[r] = fmaf(x.z, w2, acc[r]);
                acc[r] = fmaf(x.w, w3, acc[r]);
            }
        }
    } else {
        // tail (n % 32 != 0 only)
        for (int r = 0; r < ROWS_PER_WAVE; ++r) {
            if (row0 + r >= n) break;
            float a = 0.f;
            for (int k = 0; k < IN_DIM; ++k)
                a = fmaf(Xr[r * IN_DIM + k], Wl[k * OUT_DIM + lane], a);
            acc[r] = a;
        }
    }

    const float alv = a_l[lane];
    const float arv = a_r[lane];
    #pragma unroll
    for (int r = 0; r < ROWS_PER_WAVE; ++r) {
        const int row = row0 + r;
        if (row >= n) break;
        h[(size_t)row * OUT_DIM + lane] = __float2bfloat16(acc[r]);
        float vl = acc[r] * alv;
        float vr = acc[r] * arv;
        #pragma unroll
        for (int off = 32; off > 0; off >>= 1) {
            vl += __shfl_xor(vl, off);
            vr += __shfl_xor(vr, off);
        }
        if (lane == 0) { el[row] = vl; er[row] = vr; }
    }
}

// ---------------------------------------------------------------- CSR build
__global__ void degree_rank_kernel(const int* __restrict__ dst, int* __restrict__ deg,
                                   int* __restrict__ erank, int e) {
    int i = blockIdx.x * blockDim.x + threadIdx.x;
    if (i < e) erank[i] = atomicAdd(&deg[dst[i]], 1);
}

__global__ __launch_bounds__(SCAN_BLOCK) void scan_partials_kernel(
        const int* __restrict__ deg, int* __restrict__ bsum, int n)
{
    __shared__ int wsum[SCAN_BLOCK / 64];
    const int tid  = threadIdx.x;
    const int lane = tid & 63;
    const int wave = tid >> 6;
    const int base = blockIdx.x * SCAN_CHUNK + tid * SCAN_ITEMS;

    int s = 0;
    if (base + SCAN_ITEMS <= n) {
        int4 v = *(const int4*)(deg + base);
        s = v.x + v.y + v.z + v.w;
    } else {
        for (int i = 0; i < SCAN_ITEMS; ++i)
            if (base + i < n) s += deg[base + i];
    }
    #pragma unroll
    for (int off = 32; off > 0; off >>= 1) s += __shfl_xor(s, off);
    if (lane == 0) wsum[wave] = s;
    __syncthreads();
    if (tid == 0) {
        int t = 0;
        #pragma unroll
        for (int i = 0; i < SCAN_BLOCK / 64; ++i) t += wsum[i];
        bsum[blockIdx.x] = t;
    }
}

__global__ __launch_bounds__(64) void scan_bsum_kernel(int* __restrict__ bsum, int nb) {
    const int t = threadIdx.x;
    int orig = (t < nb) ? bsum[t] : 0;
    int v = orig;
    #pragma unroll
    for (int off = 1; off < 64; off <<= 1) {
        int u = __shfl_up(v, off);
        if (t >= off) v += u;
    }
    if (t < nb) bsum[t] = v - orig;   // exclusive
}

__global__ __launch_bounds__(SCAN_BLOCK) void scan_apply_kernel(
        const int* __restrict__ deg, const int* __restrict__ bsum,
        int* __restrict__ offsets, int n, int e)
{
    __shared__ int wsum[SCAN_BLOCK / 64];
    const int tid  = threadIdx.x;
    const int lane = tid & 63;
    const int wave = tid >> 6;
    const int base = blockIdx.x * SCAN_CHUNK + tid * SCAN_ITEMS;

    int v[SCAN_ITEMS];
    if (base + SCAN_ITEMS <= n) {
        int4 t4 = *(const int4*)(deg + base);
        v[0] = t4.x; v[1] = t4.y; v[2] = t4.z; v[3] = t4.w;
    } else {
        #pragma unroll
        for (int i = 0; i < SCAN_ITEMS; ++i)
            v[i] = (base + i < n) ? deg[base + i] : 0;
    }
    int s = 0;
    #pragma unroll
    for (int i = 0; i < SCAN_ITEMS; ++i) s += v[i];

    int incl = s;
    #pragma unroll
    for (int off = 1; off < 64; off <<= 1) {
        int u = __shfl_up(incl, off);
        if (lane >= off) incl += u;
    }
    if (lane == 63) wsum[wave] = incl;
    __syncthreads();
    if (wave == 0 && lane < SCAN_BLOCK / 64) {
        int ws = wsum[lane];
        int wv = ws;
        #pragma unroll
        for (int off = 1; off < SCAN_BLOCK / 64; off <<= 1) {
            int u = __shfl_up(wv, off);
            if (lane >= off) wv += u;
        }
        wsum[lane] = wv - ws;
    }
    __syncthreads();

    int run = bsum[blockIdx.x] + wsum[wave] + (incl - s);
    #pragma unroll
    for (int i = 0; i < SCAN_ITEMS; ++i) {
        int idx = base + i;
        if (idx < n) {
            offsets[idx] = run;
            run += v[i];
        }
    }
    if (blockIdx.x == 0 && tid == 0) offsets[n] = e;
}

__global__ void scatter_kernel(
        const int* __restrict__ src, const int* __restrict__ dst,
        const int* __restrict__ offsets, const int* __restrict__ erank,
        int* __restrict__ esrc, int e)
{
    int i = blockIdx.x * blockDim.x + threadIdx.x;
    if (i >= e) return;
    esrc[offsets[dst[i]] + erank[i]] = src[i];
}

// ---------------------------------------------------------------- fused softmax + aggregate
// One wave per destination node. lane = output channel. bf16 h gather, 4-way unrolled.
__global__ __launch_bounds__(256) void gat_node_kernel(
        const int* __restrict__ esrc, const int* __restrict__ offsets,
        const float* __restrict__ el, const float* __restrict__ er,
        const __hip_bfloat16* __restrict__ h, float* __restrict__ out, int n)
{
    const int node = blockIdx.x * 4 + (threadIdx.x >> 6);
    const int lane = threadIdx.x & 63;
    if (node >= n) return;

    const int start = offsets[node];
    const int deg   = offsets[node + 1] - start;

    float acc = 0.f;
    if (deg > 0) {
        const float erd = er[node];
        if (deg <= 64) {
            int   s = 0;
            float x = -INFINITY;
            if (lane < deg) {
                s = esrc[start + lane];
                x = el[s] + erd;
                x = (x > 0.f) ? x : NEG_SLOPE * x;
            }
            float m = x;
            #pragma unroll
            for (int off = 32; off > 0; off >>= 1) m = fmaxf(m, __shfl_xor(m, off));
            float ex = (lane < deg) ? __expf(x - m) : 0.f;
            float dsum = ex;
            #pragma unroll
            for (int off = 32; off > 0; off >>= 1) dsum += __shfl_xor(dsum, off);
            const float a = ex * (1.f / dsum);     // per-lane alpha

            float acc0 = 0.f, acc1 = 0.f, acc2 = 0.f, acc3 = 0.f;
            int j = 0;
            for (; j + 4 <= deg; j += 4) {
                const float a0 = __shfl(a, j),     a1 = __shfl(a, j + 1);
                const float a2 = __shfl(a, j + 2), a3 = __shfl(a, j + 3);
                const int   s0 = __shfl(s, j),     s1 = __shfl(s, j + 1);
                const int   s2 = __shfl(s, j + 2), s3 = __shfl(s, j + 3);
                const float h0 = __bfloat162float(h[(size_t)s0 * OUT_DIM + lane]);
                const float h1 = __bfloat162float(h[(size_t)s1 * OUT_DIM + lane]);
                const float h2 = __bfloat162float(h[(size_t)s2 * OUT_DIM + lane]);
                const float h3 = __bfloat162float(h[(size_t)s3 * OUT_DIM + lane]);
                acc0 = fmaf(a0, h0, acc0);
                acc1 = fmaf(a1, h1, acc1);
                acc2 = fmaf(a2, h2, acc2);
                acc3 = fmaf(a3, h3, acc3);
            }
            for (; j < deg; ++j) {
                const float aj = __shfl(a, j);
                const int   sj = __shfl(s, j);
                acc0 = fmaf(aj, __bfloat162float(h[(size_t)sj * OUT_DIM + lane]), acc0);
            }
            acc = (acc0 + acc1) + (acc2 + acc3);
        } else {
            // general chunked path (deg > 64, rare)
            float m = -INFINITY;
            for (int base = 0; base < deg; base += 64) {
                int idx = base + lane;
                if (idx < deg) {
                    int ss = esrc[start + idx];
                    float xx = el[ss] + erd;
                    xx = (xx > 0.f) ? xx : NEG_SLOPE * xx;
                    m = fmaxf(m, xx);
                }
            }
            #pragma unroll
            for (int off = 32; off > 0; off >>= 1) m = fmaxf(m, __shfl_xor(m, off));

            float dsum = 0.f;
            for (int base = 0; base < deg; base += 64) {
                int idx = base + lane;
                if (idx < deg) {
                    int ss = esrc[start + idx];
                    float xx = el[ss] + erd;
                    xx = (xx > 0.f) ? xx : NEG_SLOPE * xx;
                    dsum += __expf(xx - m);
                }
            }
            #pragma unroll
            for (int off = 32; off > 0; off >>= 1) dsum += __shfl_xor(dsum, off);
            const float inv = 1.f / dsum;

            float acc0 = 0.f, acc1 = 0.f, acc2 = 0.f, acc3 = 0.f;
            for (int base = 0; base < deg; base += 64) {
                int idx = base + lane;
                int   ss = 0;
                float av = 0.f;
                if (idx < deg) {
                    ss = esrc[start + idx];
                    float xx = el[ss] + erd;
                    xx = (xx > 0.f) ? xx : NEG_SLOPE * xx;
                    av = __expf(xx - m) * inv;
                }
                const int cnt = min(64, deg - base);
                int j = 0;
                for (; j + 4 <= cnt; j += 4) {
                    const float a0 = __shfl(av, j),     a1 = __shfl(av, j + 1);
                    const float a2 = __shfl(av, j + 2), a3 = __shfl(av, j + 3);
                    const int   s0 = __shfl(ss, j),     s1 = __shfl(ss, j + 1);
                    const int   s2 = __shfl(ss, j + 2), s3 = __shfl(ss, j + 3);
                    acc0 = fmaf(a0, __bfloat162float(h[(size_t)s0 * OUT_DIM + lane]), acc0);
                    acc1 = fmaf(a1, __bfloat162float(h[(size_t)s1 * OUT_DIM + lane]), acc1);
                    acc2 = fmaf(a2, __bfloat162float(h[(size_t)s2 * OUT_DIM + lane]), acc2);
                    acc3 = fmaf(a3, __bfloat162float(h[(size_t)s3 * OUT_DIM + lane]), acc3);
                }
                for (; j < cnt; ++j) {
                    const float aj = __shfl(av, j);
                    const int   sj = __shfl(ss, j);
                    acc0 = fmaf(aj, __bfloat162float(h[(size_t)sj * OUT_DIM + lane]), acc0);
                }
            }
            acc = (acc0 + acc1) + (acc2 + acc3);
        }
    }
    out[(size_t)node * OUT_DIM + lane] = acc;
}

// ---------------------------------------------------------------- launch
extern "C" void kernel_launch(void* const* d_in, const int* in_sizes, int n_in,
                              void* d_out, int out_size, void* d_ws, size_t ws_size,
                              hipStream_t stream) {
    const float* X   = (const float*)d_in[0];
    const int*   ei  = (const int*)  d_in[1];
    const float* W   = (const float*)d_in[2];
    const float* a_l = (const float*)d_in[3];
    const float* a_r = (const float*)d_in[4];
    float* out = (float*)d_out;

    const int n = in_sizes[0] / IN_DIM;   // 100000
    const int e = in_sizes[1] / 2;        // 1000000
    const int* src = ei;
    const int* dst = ei + e;

    char* ws = (char*)d_ws;
    auto carve = [&](size_t bytes) {
        char* p = ws;
        ws += (bytes + 255) & ~(size_t)255;
        return p;
    };
    __hip_bfloat16* h = (__hip_bfloat16*)carve((size_t)n * OUT_DIM * sizeof(__hip_bfloat16)); // 12.8 MB
    float* el      = (float*)carve((size_t)n * sizeof(float));
    float* er      = (float*)carve((size_t)n * sizeof(float));
    int*   deg     = (int*)  carve((size_t)n * sizeof(int));
    int*   offsets = (int*)  carve((size_t)(n + 1) * sizeof(int));
    int*   erank   = (int*)  carve((size_t)e * sizeof(int));             // 4 MB
    int*   esrc    = (int*)  carve((size_t)e * sizeof(int));             // 4 MB
    int*   bsum    = (int*)  carve(64 * sizeof(int));

    const int nscan = (n + SCAN_CHUNK - 1) / SCAN_CHUNK;   // 25 blocks

    hipMemsetAsync(deg, 0, (size_t)n * sizeof(int), stream);
    gemm_kernel<<<(n + ROWS_PER_BLOCK - 1) / ROWS_PER_BLOCK, 256, 0, stream>>>(
        X, W, a_l, a_r, h, el, er, n);
    degree_rank_kernel<<<(e + 255) / 256, 256, 0, stream>>>(dst, deg, erank, e);
    scan_partials_kernel<<<nscan, SCAN_BLOCK, 0, stream>>>(deg, bsum, n);
    scan_bsum_kernel<<<1, 64, 0, stream>>>(bsum, nscan);
    scan_apply_kernel<<<nscan, SCAN_BLOCK, 0, stream>>>(deg, bsum, offsets, n, e);
    scatter_kernel<<<(e + 255) / 256, 256, 0, stream>>>(src, dst, offsets, erank, esrc, e);
    gat_node_kernel<<<(n + 3) / 4, 256, 0, stream>>>(esrc, offsets, el, er, h, out, n);
}

// Round 6
// 255.364 us; speedup vs baseline: 1.0647x; 1.0647x over previous
//
#include <hip/hip_runtime.h>
#include <math.h>

#define IN_DIM 128
#define OUT_DIM 64
#define NEG_SLOPE 0.2f

typedef __attribute__((ext_vector_type(8))) short short8;
typedef __attribute__((ext_vector_type(4))) float v4f;

__device__ inline unsigned short f2bf(float f) {
    unsigned u = __float_as_uint(f);
    return (unsigned short)((u + 0x7fffu + ((u >> 16) & 1u)) >> 16);   // RNE
}

// ---------------------------------------------------------------- MFMA GEMM
// h(fp32) = X@W via bf16 MFMA (fp32 accum); el = h@a_l, er = h@a_r from acc tiles.
// Wave owns 64 rows (4 M-tiles of 16). A-frags straight from global (lane=row,
// 32B/lane contiguous, X streamed once). B-frags (W) in VGPRs for whole kernel.
__global__ __launch_bounds__(256) void gemm_mfma_kernel(
        const float* __restrict__ X, const float* __restrict__ W,
        const float* __restrict__ a_l, const float* __restrict__ a_r,
        float* __restrict__ h, float* __restrict__ el, float* __restrict__ er, int n)
{
    const int tid  = threadIdx.x;
    const int lane = tid & 63;
    const int wv   = tid >> 6;
    const int r16  = lane & 15;     // A row / B col / D col
    const int g    = lane >> 4;     // k-group (8 k each)

    // B-frags: bf[ks][nt][j] = W[ks*32 + g*8 + j][nt*16 + r16]
    short8 bf[4][4];
    #pragma unroll
    for (int ks = 0; ks < 4; ++ks) {
        #pragma unroll
        for (int nt = 0; nt < 4; ++nt) {
            const float* wp = W + (size_t)(ks * 32 + g * 8) * OUT_DIM + nt * 16 + r16;
            short8 b;
            #pragma unroll
            for (int j = 0; j < 8; ++j)
                b[j] = (short)f2bf(wp[(size_t)j * OUT_DIM]);
            bf[ks][nt] = b;
        }
    }

    const float alv0 = a_l[r16],      alv1 = a_l[16 + r16],
                alv2 = a_l[32 + r16], alv3 = a_l[48 + r16];
    const float arv0 = a_r[r16],      arv1 = a_r[16 + r16],
                arv2 = a_r[32 + r16], arv3 = a_r[48 + r16];

    const int wave_row0 = blockIdx.x * 256 + wv * 64;

    #pragma unroll
    for (int mt = 0; mt < 4; ++mt) {
        const int row0m = wave_row0 + mt * 16;
        if (row0m >= n) break;

        const int rowA = min(row0m + r16, n - 1);     // clamp for tail
        const float* xp = X + (size_t)rowA * IN_DIM + g * 8;

        v4f acc0 = {0.f,0.f,0.f,0.f}, acc1 = {0.f,0.f,0.f,0.f},
            acc2 = {0.f,0.f,0.f,0.f}, acc3 = {0.f,0.f,0.f,0.f};

        #pragma unroll
        for (int ks = 0; ks < 4; ++ks) {
            const float4 xa = *(const float4*)(xp + ks * 32);
            const float4 xb = *(const float4*)(xp + ks * 32 + 4);
            short8 a;
            a[0] = (short)f2bf(xa.x); a[1] = (short)f2bf(xa.y);
            a[2] = (short)f2bf(xa.z); a[3] = (short)f2bf(xa.w);
            a[4] = (short)f2bf(xb.x); a[5] = (short)f2bf(xb.y);
            a[6] = (short)f2bf(xb.z); a[7] = (short)f2bf(xb.w);
            acc0 = __builtin_amdgcn_mfma_f32_16x16x32_bf16(a, bf[ks][0], acc0, 0, 0, 0);
            acc1 = __builtin_amdgcn_mfma_f32_16x16x32_bf16(a, bf[ks][1], acc1, 0, 0, 0);
            acc2 = __builtin_amdgcn_mfma_f32_16x16x32_bf16(a, bf[ks][2], acc2, 0, 0, 0);
            acc3 = __builtin_amdgcn_mfma_f32_16x16x32_bf16(a, bf[ks][3], acc3, 0, 0, 0);
        }

        // D layout: row = g*4 + reg, col = nt*16 + r16   [m89 verified]
        #pragma unroll
        for (int reg = 0; reg < 4; ++reg) {
            const int row = row0m + g * 4 + reg;
            if (row < n) {
                float* hp = h + (size_t)row * OUT_DIM + r16;
                hp[0]  = acc0[reg];
                hp[16] = acc1[reg];
                hp[32] = acc2[reg];
                hp[48] = acc3[reg];
            }
        }

        #pragma unroll
        for (int reg = 0; reg < 4; ++reg) {
            float t = acc0[reg]*alv0 + acc1[reg]*alv1 + acc2[reg]*alv2 + acc3[reg]*alv3;
            float u = acc0[reg]*arv0 + acc1[reg]*arv1 + acc2[reg]*arv2 + acc3[reg]*arv3;
            #pragma unroll
            for (int off = 1; off < 16; off <<= 1) {   // reduce over the 16 cols
                t += __shfl_xor(t, off);
                u += __shfl_xor(u, off);
            }
            const int row = row0m + g * 4 + reg;
            if (r16 == 0 && row < n) { el[row] = t; er[row] = u; }
        }
    }
}

// ---------------------------------------------------------------- CSR build
__global__ void degree_rank_kernel(const int* __restrict__ dst, int* __restrict__ deg,
                                   int* __restrict__ erank, int e) {
    int i = blockIdx.x * blockDim.x + threadIdx.x;
    if (i < e) erank[i] = atomicAdd(&deg[dst[i]], 1);
}

// one-shot segment allocation: wave-prefix scan + one atomic per wave.
// Segments are contiguous but in arbitrary global order (gat_node only needs start+deg).
__global__ __launch_bounds__(256) void alloc_kernel(
        const int* __restrict__ deg, int* __restrict__ cursor,
        int2* __restrict__ seg, int n)
{
    const int i    = blockIdx.x * blockDim.x + threadIdx.x;
    const int lane = threadIdx.x & 63;
    const int d    = (i < n) ? deg[i] : 0;

    int incl = d;
    #pragma unroll
    for (int off = 1; off < 64; off <<= 1) {
        int u = __shfl_up(incl, off);
        if (lane >= off) incl += u;
    }
    int base = 0;
    if (lane == 63) base = atomicAdd(cursor, incl);
    base = __shfl(base, 63);
    if (i < n) seg[i] = make_int2(base + incl - d, d);
}

// atomic-free scatter using precomputed rank
__global__ void scatter_kernel(
        const int* __restrict__ src, const int* __restrict__ dst,
        const int2* __restrict__ seg, const int* __restrict__ erank,
        int* __restrict__ esrc, int e)
{
    int i = blockIdx.x * blockDim.x + threadIdx.x;
    if (i >= e) return;
    esrc[((const int*)seg)[2 * dst[i]] + erank[i]] = src[i];
}

// ---------------------------------------------------------------- fused softmax + aggregate
// One wave per destination node. lane = output channel. fp32 h, 4-way unrolled gather.
__global__ __launch_bounds__(256) void gat_node_kernel(
        const int* __restrict__ esrc, const int2* __restrict__ seg,
        const float* __restrict__ el, const float* __restrict__ er,
        const float* __restrict__ h, float* __restrict__ out, int n)
{
    const int node = blockIdx.x * 4 + (threadIdx.x >> 6);
    const int lane = threadIdx.x & 63;
    if (node >= n) return;

    const int2 sg   = seg[node];
    const int start = sg.x;
    const int deg   = sg.y;

    float acc = 0.f;
    if (deg > 0) {
        const float erd = er[node];
        if (deg <= 64) {
            int   s = 0;
            float x = -INFINITY;
            if (lane < deg) {
                s = esrc[start + lane];
                x = el[s] + erd;
                x = (x > 0.f) ? x : NEG_SLOPE * x;
            }
            float m = x;
            #pragma unroll
            for (int off = 32; off > 0; off >>= 1) m = fmaxf(m, __shfl_xor(m, off));
            float ex = (lane < deg) ? __expf(x - m) : 0.f;
            float dsum = ex;
            #pragma unroll
            for (int off = 32; off > 0; off >>= 1) dsum += __shfl_xor(dsum, off);
            const float a = ex * (1.f / dsum);     // per-lane alpha

            float acc0 = 0.f, acc1 = 0.f, acc2 = 0.f, acc3 = 0.f;
            int j = 0;
            for (; j + 4 <= deg; j += 4) {
                const float a0 = __shfl(a, j),     a1 = __shfl(a, j + 1);
                const float a2 = __shfl(a, j + 2), a3 = __shfl(a, j + 3);
                const int   s0 = __shfl(s, j),     s1 = __shfl(s, j + 1);
                const int   s2 = __shfl(s, j + 2), s3 = __shfl(s, j + 3);
                const float h0 = h[(size_t)s0 * OUT_DIM + lane];
                const float h1 = h[(size_t)s1 * OUT_DIM + lane];
                const float h2 = h[(size_t)s2 * OUT_DIM + lane];
                const float h3 = h[(size_t)s3 * OUT_DIM + lane];
                acc0 = fmaf(a0, h0, acc0);
                acc1 = fmaf(a1, h1, acc1);
                acc2 = fmaf(a2, h2, acc2);
                acc3 = fmaf(a3, h3, acc3);
            }
            for (; j < deg; ++j) {
                const float aj = __shfl(a, j);
                const int   sj = __shfl(s, j);
                acc0 = fmaf(aj, h[(size_t)sj * OUT_DIM + lane], acc0);
            }
            acc = (acc0 + acc1) + (acc2 + acc3);
        } else {
            // general chunked path (deg > 64, rare)
            float m = -INFINITY;
            for (int base = 0; base < deg; base += 64) {
                int idx = base + lane;
                if (idx < deg) {
                    int ss = esrc[start + idx];
                    float xx = el[ss] + erd;
                    xx = (xx > 0.f) ? xx : NEG_SLOPE * xx;
                    m = fmaxf(m, xx);
                }
            }
            #pragma unroll
            for (int off = 32; off > 0; off >>= 1) m = fmaxf(m, __shfl_xor(m, off));

            float dsum = 0.f;
            for (int base = 0; base < deg; base += 64) {
                int idx = base + lane;
                if (idx < deg) {
                    int ss = esrc[start + idx];
                    float xx = el[ss] + erd;
                    xx = (xx > 0.f) ? xx : NEG_SLOPE * xx;
                    dsum += __expf(xx - m);
                }
            }
            #pragma unroll
            for (int off = 32; off > 0; off >>= 1) dsum += __shfl_xor(dsum, off);
            const float inv = 1.f / dsum;

            float acc0 = 0.f, acc1 = 0.f, acc2 = 0.f, acc3 = 0.f;
            for (int base = 0; base < deg; base += 64) {
                int idx = base + lane;
                int   ss = 0;
                float av = 0.f;
                if (idx < deg) {
                    ss = esrc[start + idx];
                    float xx = el[ss] + erd;
                    xx = (xx > 0.f) ? xx : NEG_SLOPE * xx;
                    av = __expf(xx - m) * inv;
                }
                const int cnt = min(64, deg - base);
                int j = 0;
                for (; j + 4 <= cnt; j += 4) {
                    const float a0 = __shfl(av, j),     a1 = __shfl(av, j + 1);
                    const float a2 = __shfl(av, j + 2), a3 = __shfl(av, j + 3);
                    const int   s0 = __shfl(ss, j),     s1 = __shfl(ss, j + 1);
                    const int   s2 = __shfl(ss, j + 2), s3 = __shfl(ss, j + 3);
                    acc0 = fmaf(a0, h[(size_t)s0 * OUT_DIM + lane], acc0);
                    acc1 = fmaf(a1, h[(size_t)s1 * OUT_DIM + lane], acc1);
                    acc2 = fmaf(a2, h[(size_t)s2 * OUT_DIM + lane], acc2);
                    acc3 = fmaf(a3, h[(size_t)s3 * OUT_DIM + lane], acc3);
                }
                for (; j < cnt; ++j) {
                    const float aj = __shfl(av, j);
                    const int   sj = __shfl(ss, j);
                    acc0 = fmaf(aj, h[(size_t)sj * OUT_DIM + lane], acc0);
                }
            }
            acc = (acc0 + acc1) + (acc2 + acc3);
        }
    }
    out[(size_t)node * OUT_DIM + lane] = acc;
}

// ---------------------------------------------------------------- launch
extern "C" void kernel_launch(void* const* d_in, const int* in_sizes, int n_in,
                              void* d_out, int out_size, void* d_ws, size_t ws_size,
                              hipStream_t stream) {
    const float* X   = (const float*)d_in[0];
    const int*   ei  = (const int*)  d_in[1];
    const float* W   = (const float*)d_in[2];
    const float* a_l = (const float*)d_in[3];
    const float* a_r = (const float*)d_in[4];
    float* out = (float*)d_out;

    const int n = in_sizes[0] / IN_DIM;   // 100000
    const int e = in_sizes[1] / 2;        // 1000000
    const int* src = ei;
    const int* dst = ei + e;

    char* ws = (char*)d_ws;
    auto carve = [&](size_t bytes) {
        char* p = ws;
        ws += (bytes + 255) & ~(size_t)255;
        return p;
    };
    float* h     = (float*)carve((size_t)n * OUT_DIM * sizeof(float));   // 25.6 MB
    float* el    = (float*)carve((size_t)n * sizeof(float));
    float* er    = (float*)carve((size_t)n * sizeof(float));
    int*   degc  = (int*)  carve((size_t)(n + 1) * sizeof(int));         // deg + cursor
    int2*  seg   = (int2*) carve((size_t)n * sizeof(int2));
    int*   erank = (int*)  carve((size_t)e * sizeof(int));               // 4 MB
    int*   esrc  = (int*)  carve((size_t)e * sizeof(int));               // 4 MB
    int*   deg    = degc;
    int*   cursor = degc + n;

    hipMemsetAsync(degc, 0, (size_t)(n + 1) * sizeof(int), stream);
    gemm_mfma_kernel<<<(n + 255) / 256, 256, 0, stream>>>(X, W, a_l, a_r, h, el, er, n);
    degree_rank_kernel<<<(e + 255) / 256, 256, 0, stream>>>(dst, deg, erank, e);
    alloc_kernel<<<(n + 255) / 256, 256, 0, stream>>>(deg, cursor, seg, n);
    scatter_kernel<<<(e + 255) / 256, 256, 0, stream>>>(src, dst, seg, erank, esrc, e);
    gat_node_kernel<<<(n + 3) / 4, 256, 0, stream>>>(esrc, seg, el, er, h, out, n);
}

// Round 7
// 242.801 us; speedup vs baseline: 1.1198x; 1.0517x over previous
//
#include <hip/hip_runtime.h>
#include <math.h>

#define IN_DIM 128
#define OUT_DIM 64
#define NEG_SLOPE 0.2f

typedef __attribute__((ext_vector_type(8))) short short8;
typedef __attribute__((ext_vector_type(4))) float v4f;

__device__ inline unsigned short f2bf(float f) {
    unsigned u = __float_as_uint(f);
    return (unsigned short)((u + 0x7fffu + ((u >> 16) & 1u)) >> 16);   // RNE
}

// ---------------------------------------------------------------- MFMA GEMM
// h(fp32) = X@W via bf16 MFMA (fp32 accum); el = h@a_l, er = h@a_r from acc tiles.
// Wave owns 64 rows (4 M-tiles of 16). A-frags straight from global, B-frags in VGPRs.
__global__ __launch_bounds__(256) void gemm_mfma_kernel(
        const float* __restrict__ X, const float* __restrict__ W,
        const float* __restrict__ a_l, const float* __restrict__ a_r,
        float* __restrict__ h, float* __restrict__ el, float* __restrict__ er, int n)
{
    const int tid  = threadIdx.x;
    const int lane = tid & 63;
    const int wv   = tid >> 6;
    const int r16  = lane & 15;     // A row / B col / D col
    const int g    = lane >> 4;     // k-group (8 k each)

    // B-frags: bf[ks][nt][j] = W[ks*32 + g*8 + j][nt*16 + r16]
    short8 bf[4][4];
    #pragma unroll
    for (int ks = 0; ks < 4; ++ks) {
        #pragma unroll
        for (int nt = 0; nt < 4; ++nt) {
            const float* wp = W + (size_t)(ks * 32 + g * 8) * OUT_DIM + nt * 16 + r16;
            short8 b;
            #pragma unroll
            for (int j = 0; j < 8; ++j)
                b[j] = (short)f2bf(wp[(size_t)j * OUT_DIM]);
            bf[ks][nt] = b;
        }
    }

    const float alv0 = a_l[r16],      alv1 = a_l[16 + r16],
                alv2 = a_l[32 + r16], alv3 = a_l[48 + r16];
    const float arv0 = a_r[r16],      arv1 = a_r[16 + r16],
                arv2 = a_r[32 + r16], arv3 = a_r[48 + r16];

    const int wave_row0 = blockIdx.x * 256 + wv * 64;

    #pragma unroll
    for (int mt = 0; mt < 4; ++mt) {
        const int row0m = wave_row0 + mt * 16;
        if (row0m >= n) break;

        const int rowA = min(row0m + r16, n - 1);     // clamp for tail
        const float* xp = X + (size_t)rowA * IN_DIM + g * 8;

        v4f acc0 = {0.f,0.f,0.f,0.f}, acc1 = {0.f,0.f,0.f,0.f},
            acc2 = {0.f,0.f,0.f,0.f}, acc3 = {0.f,0.f,0.f,0.f};

        #pragma unroll
        for (int ks = 0; ks < 4; ++ks) {
            const float4 xa = *(const float4*)(xp + ks * 32);
            const float4 xb = *(const float4*)(xp + ks * 32 + 4);
            short8 a;
            a[0] = (short)f2bf(xa.x); a[1] = (short)f2bf(xa.y);
            a[2] = (short)f2bf(xa.z); a[3] = (short)f2bf(xa.w);
            a[4] = (short)f2bf(xb.x); a[5] = (short)f2bf(xb.y);
            a[6] = (short)f2bf(xb.z); a[7] = (short)f2bf(xb.w);
            acc0 = __builtin_amdgcn_mfma_f32_16x16x32_bf16(a, bf[ks][0], acc0, 0, 0, 0);
            acc1 = __builtin_amdgcn_mfma_f32_16x16x32_bf16(a, bf[ks][1], acc1, 0, 0, 0);
            acc2 = __builtin_amdgcn_mfma_f32_16x16x32_bf16(a, bf[ks][2], acc2, 0, 0, 0);
            acc3 = __builtin_amdgcn_mfma_f32_16x16x32_bf16(a, bf[ks][3], acc3, 0, 0, 0);
        }

        // D layout: row = g*4 + reg, col = nt*16 + r16
        #pragma unroll
        for (int reg = 0; reg < 4; ++reg) {
            const int row = row0m + g * 4 + reg;
            if (row < n) {
                float* hp = h + (size_t)row * OUT_DIM + r16;
                hp[0]  = acc0[reg];
                hp[16] = acc1[reg];
                hp[32] = acc2[reg];
                hp[48] = acc3[reg];
            }
        }

        #pragma unroll
        for (int reg = 0; reg < 4; ++reg) {
            float t = acc0[reg]*alv0 + acc1[reg]*alv1 + acc2[reg]*alv2 + acc3[reg]*alv3;
            float u = acc0[reg]*arv0 + acc1[reg]*arv1 + acc2[reg]*arv2 + acc3[reg]*arv3;
            #pragma unroll
            for (int off = 1; off < 16; off <<= 1) {
                t += __shfl_xor(t, off);
                u += __shfl_xor(u, off);
            }
            const int row = row0m + g * 4 + reg;
            if (r16 == 0 && row < n) { el[row] = t; er[row] = u; }
        }
    }
}

// ---------------------------------------------------------------- CSR build
__global__ void degree_rank_kernel(const int* __restrict__ dst, int* __restrict__ deg,
                                   int* __restrict__ erank, int e) {
    int i = blockIdx.x * blockDim.x + threadIdx.x;
    if (i < e) erank[i] = atomicAdd(&deg[dst[i]], 1);
}

// one-shot segment allocation: wave-prefix scan + one atomic per wave.
__global__ __launch_bounds__(256) void alloc_kernel(
        const int* __restrict__ deg, int* __restrict__ cursor,
        int2* __restrict__ seg, int n)
{
    const int i    = blockIdx.x * blockDim.x + threadIdx.x;
    const int lane = threadIdx.x & 63;
    const int d    = (i < n) ? deg[i] : 0;

    int incl = d;
    #pragma unroll
    for (int off = 1; off < 64; off <<= 1) {
        int u = __shfl_up(incl, off);
        if (lane >= off) incl += u;
    }
    int base = 0;
    if (lane == 63) base = atomicAdd(cursor, incl);
    base = __shfl(base, 63);
    if (i < n) seg[i] = make_int2(base + incl - d, d);
}

// atomic-free scatter + per-edge exp-weight computation.
// esw[p] = { src, exp(leaky_relu(el[src]+er[dst])) }  (no max subtraction:
// logits are bounded (|el|,|er| small), softmax is shift-invariant)
__global__ void scatter_w_kernel(
        const int* __restrict__ src, const int* __restrict__ dst,
        const float* __restrict__ el, const float* __restrict__ er,
        const int2* __restrict__ seg, const int* __restrict__ erank,
        int2* __restrict__ esw, int e)
{
    int i = blockIdx.x * blockDim.x + threadIdx.x;
    if (i >= e) return;
    const int s = src[i], d = dst[i];
    float x = el[s] + er[d];
    x = (x > 0.f) ? x : NEG_SLOPE * x;
    const float w = __expf(x);
    const int p = ((const int*)seg)[2 * d] + erank[i];
    esw[p] = make_int2(s, __float_as_int(w));
}

// ---------------------------------------------------------------- fused softmax + aggregate
// One wave per destination node. Half-wave per edge: lane&31 = channel pair,
// float2 gather (8B/lane). 4 edges in flight via 2-step unroll.
__global__ __launch_bounds__(256) void gat_node_kernel(
        const int2* __restrict__ esw, const int2* __restrict__ seg,
        const float* __restrict__ h, float* __restrict__ out, int n)
{
    const int node = blockIdx.x * 4 + (threadIdx.x >> 6);
    const int lane = threadIdx.x & 63;
    const int half = lane >> 5;
    const int cl   = lane & 31;
    if (node >= n) return;

    const int2 sg   = seg[node];
    const int start = sg.x;
    const int deg   = sg.y;

    float vx = 0.f, vy = 0.f;
    if (deg > 0) {
        float ax = 0.f, ay = 0.f, bx = 0.f, by = 0.f;
        if (deg <= 64) {
            int s = 0; float w = 0.f;
            if (lane < deg) {
                const int2 p = esw[start + lane];
                s = p.x; w = __int_as_float(p.y);
            }
            float dsum = w;
            #pragma unroll
            for (int off = 32; off > 0; off >>= 1) dsum += __shfl_xor(dsum, off);
            const float alpha = w * (1.f / dsum);   // lane j holds alpha_j

            int j0 = 0;
            for (; j0 + 4 <= deg; j0 += 4) {
                const int   ja = j0 + half,         jb = j0 + 2 + half;
                const float aa = __shfl(alpha, ja), ab = __shfl(alpha, jb);
                const int   sa = __shfl(s, ja),     sb = __shfl(s, jb);
                const float2 ha = *(const float2*)(h + (size_t)sa * OUT_DIM + 2 * cl);
                const float2 hb = *(const float2*)(h + (size_t)sb * OUT_DIM + 2 * cl);
                ax = fmaf(aa, ha.x, ax); ay = fmaf(aa, ha.y, ay);
                bx = fmaf(ab, hb.x, bx); by = fmaf(ab, hb.y, by);
            }
            for (; j0 < deg; j0 += 2) {
                const int j = j0 + half;
                if (j < deg) {
                    const float aj = __shfl(alpha, j);
                    const int   sj = __shfl(s, j);
                    const float2 hj = *(const float2*)(h + (size_t)sj * OUT_DIM + 2 * cl);
                    ax = fmaf(aj, hj.x, ax); ay = fmaf(aj, hj.y, ay);
                }
            }
        } else {
            // chunked (deg > 64, rare)
            float dsum = 0.f;
            for (int base = 0; base < deg; base += 64) {
                const int idx = base + lane;
                if (idx < deg) dsum += __int_as_float(esw[start + idx].y);
            }
            #pragma unroll
            for (int off = 32; off > 0; off >>= 1) dsum += __shfl_xor(dsum, off);
            const float inv = 1.f / dsum;

            for (int base = 0; base < deg; base += 64) {
                const int idx = base + lane;
                const int cnt = min(64, deg - base);
                int s = 0; float w = 0.f;
                if (idx < deg) {
                    const int2 p = esw[start + idx];
                    s = p.x; w = __int_as_float(p.y);
                }
                const float alpha = w * inv;
                int j0 = 0;
                for (; j0 + 4 <= cnt; j0 += 4) {
                    const int   ja = j0 + half,         jb = j0 + 2 + half;
                    const float aa = __shfl(alpha, ja), ab = __shfl(alpha, jb);
                    const int   sa = __shfl(s, ja),     sb = __shfl(s, jb);
                    const float2 ha = *(const float2*)(h + (size_t)sa * OUT_DIM + 2 * cl);
                    const float2 hb = *(const float2*)(h + (size_t)sb * OUT_DIM + 2 * cl);
                    ax = fmaf(aa, ha.x, ax); ay = fmaf(aa, ha.y, ay);
                    bx = fmaf(ab, hb.x, bx); by = fmaf(ab, hb.y, by);
                }
                for (; j0 < cnt; j0 += 2) {
                    const int j = j0 + half;
                    if (j < cnt) {
                        const float aj = __shfl(alpha, j);
                        const int   sj = __shfl(s, j);
                        const float2 hj = *(const float2*)(h + (size_t)sj * OUT_DIM + 2 * cl);
                        ax = fmaf(aj, hj.x, ax); ay = fmaf(aj, hj.y, ay);
                    }
                }
            }
        }
        vx = ax + bx; vy = ay + by;
        vx += __shfl_xor(vx, 32);
        vy += __shfl_xor(vy, 32);
    }
    if (half == 0) {
        float2 o; o.x = vx; o.y = vy;
        *(float2*)(out + (size_t)node * OUT_DIM + 2 * cl) = o;
    }
}

// ---------------------------------------------------------------- launch
extern "C" void kernel_launch(void* const* d_in, const int* in_sizes, int n_in,
                              void* d_out, int out_size, void* d_ws, size_t ws_size,
                              hipStream_t stream) {
    const float* X   = (const float*)d_in[0];
    const int*   ei  = (const int*)  d_in[1];
    const float* W   = (const float*)d_in[2];
    const float* a_l = (const float*)d_in[3];
    const float* a_r = (const float*)d_in[4];
    float* out = (float*)d_out;

    const int n = in_sizes[0] / IN_DIM;   // 100000
    const int e = in_sizes[1] / 2;        // 1000000
    const int* src = ei;
    const int* dst = ei + e;

    char* ws = (char*)d_ws;
    auto carve = [&](size_t bytes) {
        char* p = ws;
        ws += (bytes + 255) & ~(size_t)255;
        return p;
    };
    float* h     = (float*)carve((size_t)n * OUT_DIM * sizeof(float));   // 25.6 MB
    float* el    = (float*)carve((size_t)n * sizeof(float));
    float* er    = (float*)carve((size_t)n * sizeof(float));
    int*   degc  = (int*)  carve((size_t)(n + 1) * sizeof(int));         // deg + cursor
    int2*  seg   = (int2*) carve((size_t)n * sizeof(int2));
    int*   erank = (int*)  carve((size_t)e * sizeof(int));               // 4 MB
    int2*  esw   = (int2*) carve((size_t)e * sizeof(int2));              // 8 MB
    int*   deg    = degc;
    int*   cursor = degc + n;

    hipMemsetAsync(degc, 0, (size_t)(n + 1) * sizeof(int), stream);
    gemm_mfma_kernel<<<(n + 255) / 256, 256, 0, stream>>>(X, W, a_l, a_r, h, el, er, n);
    degree_rank_kernel<<<(e + 255) / 256, 256, 0, stream>>>(dst, deg, erank, e);
    alloc_kernel<<<(n + 255) / 256, 256, 0, stream>>>(deg, cursor, seg, n);
    scatter_w_kernel<<<(e + 255) / 256, 256, 0, stream>>>(src, dst, el, er, seg, erank, esw, e);
    gat_node_kernel<<<(n + 3) / 4, 256, 0, stream>>>(esw, seg, h, out, n);
}